// Round 1
// baseline (3115.552 us; speedup 1.0000x reference)
//
#include <hip/hip_runtime.h>
#include <hip/hip_fp16.h>
#include <stdint.h>

#define NB 32
#define NT 2048
#define ND 256
#define NU 256

typedef _Float16 f16x2 __attribute__((ext_vector_type(2)));

__device__ __forceinline__ float fdot2u(uint32_t a, uint32_t b, float c) {
#if __has_builtin(__builtin_amdgcn_fdot2)
  return __builtin_amdgcn_fdot2(__builtin_bit_cast(f16x2, a),
                                __builtin_bit_cast(f16x2, b), c, false);
#else
  f16x2 av = __builtin_bit_cast(f16x2, a);
  f16x2 bv = __builtin_bit_cast(f16x2, b);
  return c + (float)av.x * (float)bv.x + (float)av.y * (float)bv.y;
#endif
}

__device__ __forceinline__ uint32_t packh2(float lo, float hi) {
  f16x2 p;
  p.x = (_Float16)lo;
  p.y = (_Float16)hi;
  return __builtin_bit_cast(uint32_t, p);
}

struct SRec {
  float hbuf[NU];
  alignas(16) uint32_t h2[NU / 2];
  alignas(16) uint32_t rh2[NU / 2];
  float psz[2][NU];
  float psr[2][NU];
  float psh[2][NU];
};
struct SGemm {
  float a[64][132];  // [k][m], padded (132*4B = 33*16B -> float4-aligned rows)
  float b[64][68];   // [k][n], padded
};

// One kernel, two roles by blockIdx:
//  blocks [0, recCnt)         : GRU recurrence for chunk [t0r, t0r+chunkT), one batch each
//  blocks [recCnt, ...)       : fp32 GEMM computing x-projections for chunk starting t0g
__global__ __launch_bounds__(512) void gru_combined(
    const float* __restrict__ x, const float* __restrict__ Wz,
    const float* __restrict__ Wr, const float* __restrict__ Wh,
    const uint32_t* __restrict__ Wf16, float* __restrict__ hstate,
    float* __restrict__ out, const float* __restrict__ Gsrc,
    float* __restrict__ Gdst, int t0r, int t0g, int recCnt, int chunkT) {
  __shared__ union SM {
    SRec r;
    SGemm g;
  } sm;
  const int tid = threadIdx.x;

  if ((int)blockIdx.x < recCnt) {
    // ---------------- recurrence ----------------
    const int b = blockIdx.x;
    const int u = tid & (NU - 1);
    const int kh = tid >> 8;  // 0/1 : which half of K=256

    // load packed f16 recurrent weights into registers: 16 uint4 per gate
    uint4 wzv[16], wrv[16], whv[16];
    const uint4* W4 = (const uint4*)Wf16;
    const int wb = u * 32 + kh * 16;  // uint4 index within a gate (u*128 half2 = u*32 uint4)
#pragma unroll
    for (int j = 0; j < 16; j++) wzv[j] = W4[(0 * NU) * 32 + wb + j];
#pragma unroll
    for (int j = 0; j < 16; j++) wrv[j] = W4[(1 * NU) * 32 + wb + j];
#pragma unroll
    for (int j = 0; j < 16; j++) whv[j] = W4[(2 * NU) * 32 + wb + j];

    if (tid < NU) sm.r.hbuf[tid] = hstate[b * NU + tid];
    __syncthreads();
    if (tid < NU / 2) sm.r.h2[tid] = packh2(sm.r.hbuf[2 * tid], sm.r.hbuf[2 * tid + 1]);
    __syncthreads();

    float z = 0.f, r = 0.f, hu = 0.f;
    for (int tt = 0; tt < chunkT; ++tt) {
      // prefetch x-projections for this step (hidden under phase A compute)
      float gz = 0.f, gr = 0.f, gh = 0.f;
      if (tid < NU) {
        const float* Gp = Gsrc + (size_t)(tt * 3) * NB * NU + b * NU + u;
        gz = Gp[0];
        gr = Gp[NB * NU];
        gh = Gp[2 * NB * NU];
      }
      // phase A: z/r recurrent dots (each thread: K=128 for its u)
      float az = 0.f, ar = 0.f;
#pragma unroll
      for (int jb = 0; jb < 16; jb++) {
        uint4 hv = *(const uint4*)&sm.r.h2[(kh * 16 + jb) * 4];
        az = fdot2u(wzv[jb].x, hv.x, az);
        az = fdot2u(wzv[jb].y, hv.y, az);
        az = fdot2u(wzv[jb].z, hv.z, az);
        az = fdot2u(wzv[jb].w, hv.w, az);
        ar = fdot2u(wrv[jb].x, hv.x, ar);
        ar = fdot2u(wrv[jb].y, hv.y, ar);
        ar = fdot2u(wrv[jb].z, hv.z, ar);
        ar = fdot2u(wrv[jb].w, hv.w, ar);
      }
      sm.r.psz[kh][u] = az;
      sm.r.psr[kh][u] = ar;
      __syncthreads();
      // phase B: gates + r*h
      if (tid < NU) {
        float sz = gz + sm.r.psz[0][u] + sm.r.psz[1][u];
        float sr = gr + sm.r.psr[0][u] + sm.r.psr[1][u];
        z = 1.f / (1.f + __expf(-sz));
        r = 1.f / (1.f + __expf(-sr));
        hu = sm.r.hbuf[u];
        float rh = r * hu;
        float rh1 = __shfl_down(rh, 1);
        if ((u & 1) == 0) sm.r.rh2[u >> 1] = packh2(rh, rh1);
      }
      __syncthreads();
      // phase C: h_hat recurrent dot
      float ah = 0.f;
#pragma unroll
      for (int jb = 0; jb < 16; jb++) {
        uint4 rv = *(const uint4*)&sm.r.rh2[(kh * 16 + jb) * 4];
        ah = fdot2u(whv[jb].x, rv.x, ah);
        ah = fdot2u(whv[jb].y, rv.y, ah);
        ah = fdot2u(whv[jb].z, rv.z, ah);
        ah = fdot2u(whv[jb].w, rv.w, ah);
      }
      sm.r.psh[kh][u] = ah;
      __syncthreads();
      // phase D: blend, emit, repack h
      if (tid < NU) {
        float hh = tanhf(gh + sm.r.psh[0][u] + sm.r.psh[1][u]);
        float hn = z * hu + (1.f - z) * hh;
        sm.r.hbuf[u] = hn;
        out[((size_t)b * NT + (t0r + tt)) * NU + u] = hn;
        float hn1 = __shfl_down(hn, 1);
        if ((u & 1) == 0) sm.r.h2[u >> 1] = packh2(hn, hn1);
      }
      __syncthreads();
    }
    if (tid < NU) hstate[b * NU + tid] = sm.r.hbuf[tid];

  } else if (Gdst != nullptr) {
    // ---------------- x-projection GEMM for next chunk ----------------
    // C[M=32*chunkT, N=768] = X[M, 256] * W[256, 768], tile 128x64, 512 thr, 4x4 micro
    const int gg = (int)blockIdx.x - recCnt;
    const int mtile = gg / 12;
    const int ntile = gg - mtile * 12;
    const int g = ntile >> 2;
    const int u0 = (ntile & 3) * 64;
    const float* Wg = (g == 0) ? Wz : ((g == 1) ? Wr : Wh);
    const int ty = tid >> 4;  // 0..31 -> rows
    const int tx = tid & 15;  // 0..15 -> cols
    const int mbase = mtile * 128;
    float acc[4][4] = {{0.f}};

    for (int kk = 0; kk < 4; ++kk) {
      const int k0 = kk * 64;
      __syncthreads();
      {  // A tile: 128 rows x 64 k, store transposed [k][m]
        const int ml = tid & 127;
        const int kq = tid >> 7;  // 0..3
        const int m = mbase + ml;
        const int bb = m / chunkT;
        const int tt = m - bb * chunkT;
        const float* xp = x + ((size_t)bb * NT + t0g + tt) * ND + k0 + kq * 16;
#pragma unroll
        for (int v = 0; v < 4; ++v) {
          float4 xv = ((const float4*)xp)[v];
          sm.g.a[kq * 16 + v * 4 + 0][ml] = xv.x;
          sm.g.a[kq * 16 + v * 4 + 1][ml] = xv.y;
          sm.g.a[kq * 16 + v * 4 + 2][ml] = xv.z;
          sm.g.a[kq * 16 + v * 4 + 3][ml] = xv.w;
        }
      }
      {  // B tile: 64 k x 64 n
        const int nl = (tid & 15) * 4;
        const int kr = tid >> 4;  // 0..31
#pragma unroll
        for (int s = 0; s < 2; ++s) {
          const int krow = kr + s * 32;
          float4 wv = *(const float4*)&Wg[(size_t)(k0 + krow) * NU + u0 + nl];
          *(float4*)&sm.g.b[krow][nl] = wv;
        }
      }
      __syncthreads();
#pragma unroll 8
      for (int k = 0; k < 64; ++k) {
        const float4 av = *(const float4*)&sm.g.a[k][ty * 4];
        const float4 bv = *(const float4*)&sm.g.b[k][tx * 4];
        acc[0][0] += av.x * bv.x; acc[0][1] += av.x * bv.y; acc[0][2] += av.x * bv.z; acc[0][3] += av.x * bv.w;
        acc[1][0] += av.y * bv.x; acc[1][1] += av.y * bv.y; acc[1][2] += av.y * bv.z; acc[1][3] += av.y * bv.w;
        acc[2][0] += av.z * bv.x; acc[2][1] += av.z * bv.y; acc[2][2] += av.z * bv.z; acc[2][3] += av.z * bv.w;
        acc[3][0] += av.w * bv.x; acc[3][1] += av.w * bv.y; acc[3][2] += av.w * bv.z; acc[3][3] += av.w * bv.w;
      }
    }
    // epilogue: G[tt][gate][b][u]
#pragma unroll
    for (int i = 0; i < 4; ++i) {
      const int m = mbase + ty * 4 + i;
      const int bb = m / chunkT;
      const int tt = m - bb * chunkT;
      float4 val;
      val.x = acc[i][0]; val.y = acc[i][1]; val.z = acc[i][2]; val.w = acc[i][3];
      *(float4*)&Gdst[((size_t)(tt * 3 + g) * NB + bb) * NU + u0 + tx * 4] = val;
    }
  }
}

// one-time prep: pack recurrent weight rows [D, D+U) into f16 pairs, zero h state
__global__ void gru_prep(const float* __restrict__ Wz, const float* __restrict__ Wr,
                         const float* __restrict__ Wh, uint32_t* __restrict__ Wf16,
                         float* __restrict__ hstate) {
  const int idx = blockIdx.x * 256 + threadIdx.x;
  const int NW = 3 * NU * 128;  // half2 count
  if (idx < NW) {
    const int g = idx / (NU * 128);
    const int rem = idx - g * (NU * 128);
    const int u = rem >> 7;
    const int p = rem & 127;
    const float* Wg = (g == 0) ? Wz : ((g == 1) ? Wr : Wh);
    float w0 = Wg[(size_t)(ND + 2 * p) * NU + u];
    float w1 = Wg[(size_t)(ND + 2 * p + 1) * NU + u];
    Wf16[idx] = packh2(w0, w1);  // layout [g][u][p]
  } else {
    const int j = idx - NW;
    if (j < NB * NU) hstate[j] = 0.f;
  }
}

extern "C" void kernel_launch(void* const* d_in, const int* in_sizes, int n_in,
                              void* d_out, int out_size, void* d_ws, size_t ws_size,
                              hipStream_t stream) {
  (void)in_sizes; (void)n_in; (void)out_size;
  const float* x = (const float*)d_in[0];
  const float* Wz = (const float*)d_in[1];
  const float* Wr = (const float*)d_in[2];
  const float* Wh = (const float*)d_in[3];
  float* out = (float*)d_out;

  // pick largest chunk that fits ws: 2 G buffers + Wf16 + hstate
  int ct = 8;
  const int cands[6] = {256, 128, 64, 32, 16, 8};
  for (int i = 0; i < 6; ++i) {
    size_t need = 2ull * cands[i] * 3 * NB * NU * 4 + (1u << 20);
    if (need <= ws_size) { ct = cands[i]; break; }
  }
  const int nch = NT / ct;
  const size_t chunkBytes = (size_t)ct * 3 * NB * NU * 4;

  char* wsb = (char*)d_ws;
  float* G0 = (float*)wsb;
  float* G1 = (float*)(wsb + chunkBytes);
  uint32_t* Wf16 = (uint32_t*)(wsb + 2 * chunkBytes);
  float* hstate = (float*)(wsb + 2 * chunkBytes + (size_t)3 * NU * 128 * 4);

  const int prepThreads = 3 * NU * 128 + NB * NU;
  gru_prep<<<(prepThreads + 255) / 256, 256, 0, stream>>>(Wz, Wr, Wh, Wf16, hstate);

  // chunk 0 x-projection only
  gru_combined<<<3 * ct, 512, 0, stream>>>(x, Wz, Wr, Wh, Wf16, hstate, out,
                                           nullptr, G0, 0, 0, 0, ct);
  for (int k = 0; k < nch; ++k) {
    float* Gsrc = (k & 1) ? G1 : G0;
    float* Gdst = (k & 1) ? G0 : G1;
    const int gemmOn = (k + 1 < nch) ? 1 : 0;
    gru_combined<<<32 + (gemmOn ? 3 * ct : 0), 512, 0, stream>>>(
        x, Wz, Wr, Wh, Wf16, hstate, out, Gsrc, gemmOn ? Gdst : nullptr,
        k * ct, (k + 1) * ct, 32, ct);
  }
}

// Round 2
// 2907.648 us; speedup vs baseline: 1.0715x; 1.0715x over previous
//
#include <hip/hip_runtime.h>
#include <hip/hip_fp16.h>
#include <stdint.h>

#define NB 32
#define NT 2048
#define ND 256
#define NU 256

typedef _Float16 f16x2 __attribute__((ext_vector_type(2)));

__device__ __forceinline__ float fdot2u(uint32_t a, uint32_t b, float c) {
#if __has_builtin(__builtin_amdgcn_fdot2)
  return __builtin_amdgcn_fdot2(__builtin_bit_cast(f16x2, a),
                                __builtin_bit_cast(f16x2, b), c, false);
#else
  f16x2 av = __builtin_bit_cast(f16x2, a);
  f16x2 bv = __builtin_bit_cast(f16x2, b);
  return c + (float)av.x * (float)bv.x + (float)av.y * (float)bv.y;
#endif
}

__device__ __forceinline__ uint32_t packh2(float lo, float hi) {
  f16x2 p;
  p.x = (_Float16)lo;
  p.y = (_Float16)hi;
  return __builtin_bit_cast(uint32_t, p);
}

__device__ __forceinline__ float rcp_fast(float x) { return __builtin_amdgcn_rcpf(x); }
__device__ __forceinline__ float sigmoid_fast(float x) {
  return rcp_fast(1.f + __expf(-x));
}
__device__ __forceinline__ float tanh_fast(float x) {
  return 1.f - 2.f * rcp_fast(1.f + __expf(2.f * x));
}

struct SRec {
  float hbuf[NU];
  alignas(16) uint32_t h2[NU / 2];
  alignas(16) uint32_t rh2[NU / 2];
  float psh[NU];
};
struct SGemm {
  float a[64][132];  // [k][m], padded
  float b[64][68];   // [k][n], padded
};

// One kernel, two roles by blockIdx:
//  blocks [0, recCnt) : GRU recurrence for chunk [t0r, t0r+chunkT), one batch each
//  blocks [recCnt, .) : fp32 GEMM computing x-projections for chunk starting t0g
__global__ __launch_bounds__(512)
__attribute__((amdgpu_waves_per_eu(2, 2)))
void gru_combined(
    const float* __restrict__ x, const float* __restrict__ Wz,
    const float* __restrict__ Wr, const float* __restrict__ Wh,
    const uint32_t* __restrict__ Wf16, float* __restrict__ hstate,
    float* __restrict__ out, const float* __restrict__ Gsrc,
    float* __restrict__ Gdst, int t0r, int t0g, int recCnt, int chunkT) {
  __shared__ union SM {
    SRec r;
    SGemm g;
  } sm;
  const int tid = threadIdx.x;

  if ((int)blockIdx.x < recCnt) {
    // ---------------- recurrence ----------------
    const int b = blockIdx.x;
    const int u = tid & (NU - 1);
    const int role = tid >> 8;  // 0: z-owner (also blends), 1: r-owner

    // weights in registers (f16 pairs):
    //  role0: full Wz column (32 uint4) ; role1: full Wr column
    //  both: half of Wh column (16 uint4) split by role
    uint4 wfull[32], wh[16];
    const uint4* W4 = (const uint4*)Wf16;
    const int baseFull = role * (NU * 32) + u * 32;
#pragma unroll
    for (int j = 0; j < 32; j++) wfull[j] = W4[baseFull + j];
    const int baseH = 2 * (NU * 32) + u * 32 + role * 16;
#pragma unroll
    for (int j = 0; j < 16; j++) wh[j] = W4[baseH + j];

    float hu = 0.f;
    if (tid < NU) {
      hu = hstate[b * NU + tid];
      sm.r.hbuf[tid] = hu;
    }
    __syncthreads();
    if (tid < NU / 2) sm.r.h2[tid] = packh2(sm.r.hbuf[2 * tid], sm.r.hbuf[2 * tid + 1]);
    __syncthreads();

    const float* Gb = Gsrc + (size_t)b * NU + u;
    float* outp = out + ((size_t)b * NT + t0r) * NU + u;

    for (int tt = 0; tt < chunkT; ++tt) {
      // per-step x-projection loads (L2-resident; issued before the dots)
      float g0, g1 = 0.f;
      {
        const float* Gt = Gb + (size_t)(tt * 3) * NB * NU;
        if (role == 0) {
          g0 = Gt[0];            // gz
          g1 = Gt[2 * NB * NU];  // gh
        } else {
          g0 = Gt[NB * NU];      // gr
        }
      }
      // phase A: full-K recurrent dot (z for role0, r for role1)
      float a0 = 0.f, a1 = 0.f, a2 = 0.f, a3 = 0.f;
#pragma unroll
      for (int jb = 0; jb < 32; jb++) {
        uint4 hv = *(const uint4*)&sm.r.h2[jb * 4];
        a0 = fdot2u(wfull[jb].x, hv.x, a0);
        a1 = fdot2u(wfull[jb].y, hv.y, a1);
        a2 = fdot2u(wfull[jb].z, hv.z, a2);
        a3 = fdot2u(wfull[jb].w, hv.w, a3);
      }
      const float ssum = ((a0 + a1) + (a2 + a3)) + g0;
      float zval = 0.f;
      if (role == 1) {
        const float rr = sigmoid_fast(ssum);
        const float hprev = sm.r.hbuf[u];
        const float rh = rr * hprev;
        const float rh1 = __shfl_down(rh, 1);
        if ((u & 1) == 0) sm.r.rh2[u >> 1] = packh2(rh, rh1);
      } else {
        zval = sigmoid_fast(ssum);
      }
      __syncthreads();  // rh2 ready
      // phase C: h_hat recurrent dot, K split by role
      float c0 = 0.f, c1 = 0.f, c2 = 0.f, c3 = 0.f;
#pragma unroll
      for (int jb = 0; jb < 16; jb++) {
        uint4 rv = *(const uint4*)&sm.r.rh2[(role * 16 + jb) * 4];
        c0 = fdot2u(wh[jb].x, rv.x, c0);
        c1 = fdot2u(wh[jb].y, rv.y, c1);
        c2 = fdot2u(wh[jb].z, rv.z, c2);
        c3 = fdot2u(wh[jb].w, rv.w, c3);
      }
      const float csum = (c0 + c1) + (c2 + c3);
      if (role == 1) sm.r.psh[u] = csum;
      __syncthreads();  // psh ready
      if (role == 0) {
        const float hh = tanh_fast(g1 + csum + sm.r.psh[u]);
        const float hn = zval * hu + (1.f - zval) * hh;
        hu = hn;
        outp[0] = hn;
        sm.r.hbuf[u] = hn;
        const float hn1 = __shfl_down(hn, 1);
        if ((u & 1) == 0) sm.r.h2[u >> 1] = packh2(hn, hn1);
      }
      outp += NU;
      __syncthreads();  // h ready for next step
    }
    if (role == 0) hstate[b * NU + u] = hu;

  } else if (Gdst != nullptr) {
    // ---------------- x-projection GEMM for next chunk ----------------
    // C[M=32*chunkT, N=768] = X[M, 256] * W[256, 768], tile 128x64, 512 thr, 4x4 micro
    const int gg = (int)blockIdx.x - recCnt;
    const int mtile = gg / 12;
    const int ntile = gg - mtile * 12;
    const int g = ntile >> 2;
    const int u0 = (ntile & 3) * 64;
    const float* Wg = (g == 0) ? Wz : ((g == 1) ? Wr : Wh);
    const int ty = tid >> 4;  // 0..31 -> rows
    const int tx = tid & 15;  // 0..15 -> cols
    const int mbase = mtile * 128;
    float acc[4][4] = {{0.f}};

    for (int kk = 0; kk < 4; ++kk) {
      const int k0 = kk * 64;
      __syncthreads();
      {  // A tile: 128 rows x 64 k, store transposed [k][m]
        const int ml = tid & 127;
        const int kq = tid >> 7;  // 0..3
        const int m = mbase + ml;
        const int bb = m / chunkT;
        const int tt = m - bb * chunkT;
        const float* xp = x + ((size_t)bb * NT + t0g + tt) * ND + k0 + kq * 16;
#pragma unroll
        for (int v = 0; v < 4; ++v) {
          float4 xv = ((const float4*)xp)[v];
          sm.g.a[kq * 16 + v * 4 + 0][ml] = xv.x;
          sm.g.a[kq * 16 + v * 4 + 1][ml] = xv.y;
          sm.g.a[kq * 16 + v * 4 + 2][ml] = xv.z;
          sm.g.a[kq * 16 + v * 4 + 3][ml] = xv.w;
        }
      }
      {  // B tile: 64 k x 64 n
        const int nl = (tid & 15) * 4;
        const int kr = tid >> 4;  // 0..31
#pragma unroll
        for (int s = 0; s < 2; ++s) {
          const int krow = kr + s * 32;
          float4 wv = *(const float4*)&Wg[(size_t)(k0 + krow) * NU + u0 + nl];
          *(float4*)&sm.g.b[krow][nl] = wv;
        }
      }
      __syncthreads();
#pragma unroll 8
      for (int k = 0; k < 64; ++k) {
        const float4 av = *(const float4*)&sm.g.a[k][ty * 4];
        const float4 bv = *(const float4*)&sm.g.b[k][tx * 4];
        acc[0][0] += av.x * bv.x; acc[0][1] += av.x * bv.y; acc[0][2] += av.x * bv.z; acc[0][3] += av.x * bv.w;
        acc[1][0] += av.y * bv.x; acc[1][1] += av.y * bv.y; acc[1][2] += av.y * bv.z; acc[1][3] += av.y * bv.w;
        acc[2][0] += av.z * bv.x; acc[2][1] += av.z * bv.y; acc[2][2] += av.z * bv.z; acc[2][3] += av.z * bv.w;
        acc[3][0] += av.w * bv.x; acc[3][1] += av.w * bv.y; acc[3][2] += av.w * bv.z; acc[3][3] += av.w * bv.w;
      }
    }
    // epilogue: G[tt][gate][b][u]
#pragma unroll
    for (int i = 0; i < 4; ++i) {
      const int m = mbase + ty * 4 + i;
      const int bb = m / chunkT;
      const int tt = m - bb * chunkT;
      float4 val;
      val.x = acc[i][0]; val.y = acc[i][1]; val.z = acc[i][2]; val.w = acc[i][3];
      *(float4*)&Gdst[((size_t)(tt * 3 + g) * NB + bb) * NU + u0 + tx * 4] = val;
    }
  }
}

// one-time prep: pack recurrent weight rows [D, D+U) into f16 pairs, zero h state
__global__ void gru_prep(const float* __restrict__ Wz, const float* __restrict__ Wr,
                         const float* __restrict__ Wh, uint32_t* __restrict__ Wf16,
                         float* __restrict__ hstate) {
  const int idx = blockIdx.x * 256 + threadIdx.x;
  const int NW = 3 * NU * 128;  // half2 count
  if (idx < NW) {
    const int g = idx / (NU * 128);
    const int rem = idx - g * (NU * 128);
    const int u = rem >> 7;
    const int p = rem & 127;
    const float* Wg = (g == 0) ? Wz : ((g == 1) ? Wr : Wh);
    float w0 = Wg[(size_t)(ND + 2 * p) * NU + u];
    float w1 = Wg[(size_t)(ND + 2 * p + 1) * NU + u];
    Wf16[idx] = packh2(w0, w1);  // layout [g][u][p]
  } else {
    const int j = idx - NW;
    if (j < NB * NU) hstate[j] = 0.f;
  }
}

extern "C" void kernel_launch(void* const* d_in, const int* in_sizes, int n_in,
                              void* d_out, int out_size, void* d_ws, size_t ws_size,
                              hipStream_t stream) {
  (void)in_sizes; (void)n_in; (void)out_size;
  const float* x = (const float*)d_in[0];
  const float* Wz = (const float*)d_in[1];
  const float* Wr = (const float*)d_in[2];
  const float* Wh = (const float*)d_in[3];
  float* out = (float*)d_out;

  // pick largest chunk that fits ws: 2 G buffers + Wf16 + hstate
  int ct = 8;
  const int cands[6] = {256, 128, 64, 32, 16, 8};
  for (int i = 0; i < 6; ++i) {
    size_t need = 2ull * cands[i] * 3 * NB * NU * 4 + (1u << 20);
    if (need <= ws_size) { ct = cands[i]; break; }
  }
  const int nch = NT / ct;
  const size_t chunkBytes = (size_t)ct * 3 * NB * NU * 4;

  char* wsb = (char*)d_ws;
  float* G0 = (float*)wsb;
  float* G1 = (float*)(wsb + chunkBytes);
  uint32_t* Wf16 = (uint32_t*)(wsb + 2 * chunkBytes);
  float* hstate = (float*)(wsb + 2 * chunkBytes + (size_t)3 * NU * 128 * 4);

  const int prepThreads = 3 * NU * 128 + NB * NU;
  gru_prep<<<(prepThreads + 255) / 256, 256, 0, stream>>>(Wz, Wr, Wh, Wf16, hstate);

  // chunk 0 x-projection only
  gru_combined<<<3 * ct, 512, 0, stream>>>(x, Wz, Wr, Wh, Wf16, hstate, out,
                                           nullptr, G0, 0, 0, 0, ct);
  for (int k = 0; k < nch; ++k) {
    float* Gsrc = (k & 1) ? G1 : G0;
    float* Gdst = (k & 1) ? G0 : G1;
    const int gemmOn = (k + 1 < nch) ? 1 : 0;
    gru_combined<<<32 + (gemmOn ? 3 * ct : 0), 512, 0, stream>>>(
        x, Wz, Wr, Wh, Wf16, hstate, out, Gsrc, gemmOn ? Gdst : nullptr,
        k * ct, (k + 1) * ct, 32, ct);
  }
}